// Round 15
// baseline (362.300 us; speedup 1.0000x reference)
//
#include <hip/hip_runtime.h>

#define S_DIM 8192
#define NTRI256 528   // triangle of 256-tiles: 32*33/2
#define NWORK2 1088   // half-row sink work blocks: 2 x sum_R (floor(R/4)+1)

typedef __attribute__((ext_vector_type(8))) short short8v;
typedef __attribute__((ext_vector_type(16))) float f32x16;
typedef __attribute__((ext_vector_type(2))) float f32x2;

__device__ inline unsigned short f32_to_bf16(float f) {
    unsigned int b = __builtin_bit_cast(unsigned int, f);
    unsigned int lsb = (b >> 16) & 1u;
    b += 0x7fffu + lsb;
    return (unsigned short)(b >> 16);
}
__device__ inline unsigned int fkey(float f) {
    unsigned int b = __builtin_bit_cast(unsigned int, f);
    return (b & 0x80000000u) ? ~b : (b | 0x80000000u);
}
__device__ inline float fkey_inv(unsigned int k) {
    unsigned int b = (k & 0x80000000u) ? (k & 0x7FFFFFFFu) : ~k;
    return __builtin_bit_cast(float, b);
}

// ---- fp8 e4m3fn helpers (values all positive) ----
__device__ inline unsigned int f32_to_fp8_scalar(float f) {
#if __has_builtin(__builtin_amdgcn_cvt_pk_fp8_f32)
    return (unsigned int)__builtin_amdgcn_cvt_pk_fp8_f32(f, f, 0, false) & 0xFFu;
#else
    if (f < 0.015625f) return (unsigned int)__float2int_rn(f * 512.0f);
    unsigned int b = __builtin_bit_cast(unsigned int, f);
    unsigned int r = b + 0x7FFFFu + ((b >> 20) & 1u);
    return (r >> 20) - 960u;
#endif
}
__device__ inline unsigned int pack_fp8x4(float a, float b, float c, float d) {
#if __has_builtin(__builtin_amdgcn_cvt_pk_fp8_f32)
    int w = __builtin_amdgcn_cvt_pk_fp8_f32(a, b, 0, false);
    w = __builtin_amdgcn_cvt_pk_fp8_f32(c, d, w, true);
    return (unsigned int)w;
#else
    return f32_to_fp8_scalar(a) | (f32_to_fp8_scalar(b) << 8) |
           (f32_to_fp8_scalar(c) << 16) | (f32_to_fp8_scalar(d) << 24);
#endif
}
#if !__has_builtin(__builtin_amdgcn_cvt_pk_f32_fp8)
__device__ inline float fp8_byte_to_f32(unsigned int u) {
    unsigned int e = (u >> 3) & 15u, m = u & 7u;
    if (e == 0) return (float)m * 0x1p-9f;
    return __builtin_bit_cast(float, ((e + 120u) << 23) | (m << 20));
}
#endif
__device__ inline void fp8x4_to_f32(unsigned int d, float* o) {
#if __has_builtin(__builtin_amdgcn_cvt_pk_f32_fp8)
    f32x2 lo = __builtin_amdgcn_cvt_pk_f32_fp8((int)d, false);
    f32x2 hi = __builtin_amdgcn_cvt_pk_f32_fp8((int)d, true);
    o[0] = lo[0]; o[1] = lo[1]; o[2] = hi[0]; o[3] = hi[1];
#else
    o[0] = fp8_byte_to_f32(d & 0xFFu);
    o[1] = fp8_byte_to_f32((d >> 8) & 0xFFu);
    o[2] = fp8_byte_to_f32((d >> 16) & 0xFFu);
    o[3] = fp8_byte_to_f32((d >> 24) & 0xFFu);
#endif
}

// triangle enumeration: id -> (bi <= bj)
__device__ inline void tri_map(int id, int& bi, int& bj) {
    int j = (int)((sqrtf(8.0f * (float)id + 1.0f) - 1.0f) * 0.5f);
    while ((j + 1) * (j + 2) / 2 <= id) ++j;
    while (j * (j + 1) / 2 > id) --j;
    bj = j;
    bi = id - j * (j + 1) / 2;
}
// sink work enumeration: id in [0,544) -> (R, s) with 4s <= R.
__device__ inline void work_map(int id, int& R, int& s) {
    int g = (int)((sqrtf(1.0f + 2.0f * (float)id) - 1.0f) * 0.5f);
    while (2 * (g + 1) * (g + 2) <= id) ++g;
    while (2 * g * (g + 1) > id) --g;
    int rem = id - 2 * g * (g + 1);
    int r = rem / (g + 1);
    s = rem - r * (g + 1);
    R = 4 * g + r;
}

// 4 rows per 256-thread block (wave per row): L2-normalize -> bf16 fragment-major
__global__ __launch_bounds__(256) void normalize_kernel(const float* __restrict__ z,
                                                        unsigned int* __restrict__ znb,
                                                        float* __restrict__ y0,
                                                        float* __restrict__ y1,
                                                        unsigned int* __restrict__ minslot,
                                                        float* __restrict__ lossacc,
                                                        unsigned int* __restrict__ cnt) {
    int t = threadIdx.x;
    int w = t >> 6, lane = t & 63;
    int row = blockIdx.x * 4 + w;
    float2 val = ((const float2*)(z + (size_t)row * 128))[lane];
    float ss = val.x * val.x + val.y * val.y;
    #pragma unroll
    for (int off = 32; off; off >>= 1) ss += __shfl_xor(ss, off);
    float inv = 1.0f / sqrtf(ss);
    float2 o; o.x = val.x * inv; o.y = val.y * inv;
    unsigned int pk = (unsigned int)f32_to_bf16(o.x) | ((unsigned int)f32_to_bf16(o.y) << 16);
    // fragment-major: granule(row,chunk) = (row>>5)*512 + chunk*32 + (row&31)
    znb[((row >> 5) * 512 + (lane >> 2) * 32 + (row & 31)) * 4 + (lane & 3)] = pk;
    if (lane == 0) {
        y0[row] = 1.0f;
        y1[row] = 0.0f;
    }
    if (blockIdx.x == 0 && t == 0) { *minslot = 0xFFFFFFFFu; *lossacc = 0.0f; *cnt = 0u; }
}

// Triangle GEMM, 256x256 tile per 512-thread block; 8 waves in 4x2 (wave tile 64x128).
// 64 MFMAs/wave amortize load latency; 528 blocks amortize per-block overheads.
// Epilogue: two 128-col halves through a 32 KB swizzled Tl, coalesced transposed store.
// Pair-loss folded for tiles with bj-bi==16; diag stored 0 (exact fix in sink pass).
__global__ __launch_bounds__(512, 4) void gemm_exp_mfma(const short* __restrict__ znb,
                                                        unsigned char* __restrict__ K8,
                                                        unsigned int* __restrict__ minslot,
                                                        float* __restrict__ lossacc) {
    __shared__ unsigned int Tl[128 * 64];   // 32 KB, one column-half
    __shared__ float wmins[8];
    int bi, bj;
    tri_map(blockIdx.x, bi, bj);            // bi <= bj in [0,32)
    const bool pairblk = (bj - bi == 16);
    const bool diagblk = (bi == bj);
    const int t = threadIdx.x;
    const int lane = t & 63, w = t >> 6;
    const int tr = w >> 1, tc = w & 1;      // wave tile: rows tr*64, cols tc*128
    const int cl = lane & 31, hi = lane >> 5;
    const int rA0 = bi * 256 + tr * 64;
    const int cB0 = bj * 256 + tc * 128;
    const short8v* Z = (const short8v*)znb;

    f32x16 acc[2][4];
    #pragma unroll
    for (int ra = 0; ra < 2; ++ra)
        #pragma unroll
        for (int nb = 0; nb < 4; ++nb)
            #pragma unroll
            for (int e = 0; e < 16; ++e) acc[ra][nb][e] = 0.0f;

    #pragma unroll
    for (int step = 0; step < 8; ++step) {
        const int chunk = step * 2 + hi;
        short8v af[2], bf[4];
        #pragma unroll
        for (int ra = 0; ra < 2; ++ra)
            af[ra] = Z[((rA0 + ra * 32) >> 5) * 512 + chunk * 32 + cl];
        #pragma unroll
        for (int nb = 0; nb < 4; ++nb)
            bf[nb] = Z[((cB0 + nb * 32) >> 5) * 512 + chunk * 32 + cl];
        #pragma unroll
        for (int ra = 0; ra < 2; ++ra)
            #pragma unroll
            for (int nb = 0; nb < 4; ++nb)
                acc[ra][nb] = __builtin_amdgcn_mfma_f32_32x32x16_bf16(af[ra], bf[nb], acc[ra][nb], 0, 0, 0);
    }

    // C layout: col = lane&31, row = (reg&3) + 8*(reg>>2) + 4*(lane>>5)
    float mn = 3.0e38f;
    float pl = 0.0f;
    #pragma unroll
    for (int h = 0; h < 2; ++h) {
        if (tc == h) {   // wave-uniform: the 4 waves owning this column half
            #pragma unroll
            for (int ra = 0; ra < 2; ++ra)
                #pragma unroll
                for (int nb = 0; nb < 4; ++nb) {
                    int colL2 = nb * 32 + cl;           // 0..127 within half
                    int colG = cB0 + colL2;
                    int swz = colL2 & 63;
                    #pragma unroll
                    for (int g = 0; g < 4; ++g) {
                        int rowG = rA0 + ra * 32 + 8 * g + 4 * hi;
                        float ev[4];
                        #pragma unroll
                        for (int kk = 0; kk < 4; ++kk) {
                            float c = acc[ra][nb][g * 4 + kk];
                            mn = fminf(mn, c);
                            if (pairblk && (colG - rowG - kk) == 4096) pl += 20.0f * (c - 1.0f);
                            ev[kk] = __expf(10.0f * fminf(c, 0.6f));
                        }
                        if (diagblk) {
                            #pragma unroll
                            for (int kk = 0; kk < 4; ++kk)
                                if (rowG + kk == colG) ev[kk] = 0.0f;
                        }
                        unsigned int wv = pack_fp8x4(ev[0], ev[1], ev[2], ev[3]);
                        int r4b = tr * 16 + ra * 8 + 2 * g + hi;   // 0..63
                        Tl[colL2 * 64 + (r4b ^ swz)] = wv;
                    }
                }
        }
        __syncthreads();
        // coalesced store of this transposed half at lower-triangle block (bj, bi):
        // global row = bj*256 + h*128 + c2, cols bi*256 + 256B span
        const size_t gbase = (size_t)(bj * 256 + h * 128) * S_DIM + (size_t)bi * 256;
        const int c2 = t >> 2;               // 0..127
        const int sw2 = c2 & 63;
        #pragma unroll
        for (int i = 0; i < 4; ++i) {
            int dq = (t & 3) * 4 + i * 16;   // 4-lane groups cover 64B contiguous
            uint4 wv;
            wv.x = Tl[c2 * 64 + ((dq + 0) ^ sw2)];
            wv.y = Tl[c2 * 64 + ((dq + 1) ^ sw2)];
            wv.z = Tl[c2 * 64 + ((dq + 2) ^ sw2)];
            wv.w = Tl[c2 * 64 + ((dq + 3) ^ sw2)];
            *(uint4*)(K8 + gbase + (size_t)c2 * S_DIM + dq * 4) = wv;
        }
        __syncthreads();   // protect Tl for the next half's writers
    }

    #pragma unroll
    for (int off = 32; off; off >>= 1) mn = fminf(mn, __shfl_xor(mn, off));
    if (lane == 0) wmins[w] = mn;
    if (pairblk) {
        #pragma unroll
        for (int off = 32; off; off >>= 1) pl += __shfl_xor(pl, off);
        if (lane == 0) atomicAdd(lossacc, pl);
    }
    __syncthreads();
    if (t == 0) {
        float bmin = wmins[0];
        #pragma unroll
        for (int k = 1; k < 8; ++k) bmin = fminf(bmin, wmins[k]);
        atomicMin(minslot, fkey(bmin));
    }
}

// One Sinkhorn pass, 1088 half-row work blocks (R12-proven, byte-identical).
__global__ __launch_bounds__(256, 4) void sink_pass_kernel(const unsigned char* __restrict__ K8,
                                                           const float* __restrict__ yprev,
                                                           float* __restrict__ ycur,
                                                           float* __restrict__ ynext,
                                                           const unsigned int* __restrict__ minslot) {
    __shared__ float xsc[512];
    __shared__ float xsr[64];
    __shared__ float rdp[64 * 33];
    __shared__ float csum[4 * 512];
    const int t = threadIdx.x;
    const int id = blockIdx.x;
    if (id < 32) ynext[id * 256 + t] = 0.0f;

    int R, s;
    work_map(id >> 1, R, s);
    const int h = id & 1;
    const int q0 = s * 4;
    const int rbase = R * 128 + h * 64;
    if (t < 64) xsr[t] = 1.0f / yprev[rbase + t];
    xsc[t]       = 1.0f / yprev[q0 * 128 + t];
    xsc[t + 256] = 1.0f / yprev[q0 * 128 + 256 + t];

    const int w = t >> 6, lane = t & 63, half = lane >> 5, d = lane & 31;
    const int C = q0 + (d >> 3);
    const bool tvalid = (C <= R);
    const bool cvalid = (C < R);

    uint4 kreg[8];
    const unsigned char* base = K8 + (size_t)(rbase + (w << 4) + half) * S_DIM
                                   + q0 * 128 + d * 16;
    if (tvalid) {
        #pragma unroll
        for (int i2 = 0; i2 < 8; ++i2)
            kreg[i2] = *(const uint4*)(base + (size_t)(i2 << 1) * S_DIM);
    } else {
        #pragma unroll
        for (int i2 = 0; i2 < 8; ++i2) kreg[i2] = (uint4){0u, 0u, 0u, 0u};
    }
    __syncthreads();

    float xr[16];
    #pragma unroll
    for (int u = 0; u < 4; ++u)
        *(float4*)&xr[u * 4] = *(const float4*)&xsc[d * 16 + u * 4];
    float ca[16];
    #pragma unroll
    for (int e = 0; e < 16; ++e) ca[e] = 0.0f;

    #pragma unroll
    for (int i2 = 0; i2 < 8; ++i2) {
        int row = (w << 4) + (i2 << 1) + half;
        float f[16];
        fp8x4_to_f32(kreg[i2].x, f + 0);  fp8x4_to_f32(kreg[i2].y, f + 4);
        fp8x4_to_f32(kreg[i2].z, f + 8);  fp8x4_to_f32(kreg[i2].w, f + 12);
        float rd = 0.0f;
        #pragma unroll
        for (int e = 0; e < 16; ++e) rd += f[e] * xr[e];
        if (cvalid) {
            float xv = xsr[row];
            #pragma unroll
            for (int e = 0; e < 16; ++e) ca[e] += f[e] * xv;
        }
        rdp[row * 33 + d] = rd;
    }
    #pragma unroll
    for (int e = 0; e < 16; ++e) ca[e] += __shfl_xor(ca[e], 32);
    if (half == 0) {
        #pragma unroll
        for (int u = 0; u < 4; ++u) {
            float4 v; v.x = ca[u*4]; v.y = ca[u*4+1]; v.z = ca[u*4+2]; v.w = ca[u*4+3];
            *(float4*)&csum[w * 512 + d * 16 + u * 4] = v;
        }
    }
    __syncthreads();
    if (t < 64) {
        float sum = 0.0f;
        #pragma unroll
        for (int k = 0; k < 32; ++k) sum += rdp[t * 33 + k];
        if (s == (R >> 2))
            sum += __expf(10.0f * fkey_inv(*minslot)) * xsr[t];
        atomicAdd(&ycur[rbase + t], sum);
    }
    #pragma unroll
    for (int u = 0; u < 2; ++u) {
        int cc = t + u * 256;
        int Cc = q0 + (cc >> 7);
        if (Cc < R)
            atomicAdd(&ycur[q0 * 128 + cc],
                      csum[cc] + csum[512 + cc] + csum[1024 + cc] + csum[1536 + cc]);
    }
}

// Final loss: pair term already in lossacc; add sum_i (10 - log y11[i] - log y10[i]).
__global__ __launch_bounds__(256) void loss_kernel(const float* __restrict__ y11,
                                                   const float* __restrict__ y10,
                                                   float* __restrict__ lossacc,
                                                   unsigned int* __restrict__ cnt,
                                                   float* __restrict__ out) {
    __shared__ float wpart[4];
    const int t = threadIdx.x;
    int i = blockIdx.x * 256 + t;
    float val = 10.0f - __logf(y11[i]) - __logf(y10[i]);
    #pragma unroll
    for (int off = 32; off; off >>= 1) val += __shfl_xor(val, off);
    if ((t & 63) == 0) wpart[t >> 6] = val;
    __syncthreads();
    if (t == 0) {
        atomicAdd(lossacc, wpart[0] + wpart[1] + wpart[2] + wpart[3]);
        __threadfence();
        unsigned int done = atomicAdd(cnt, 1u);
        if (done == gridDim.x - 1) {
            __threadfence();
            out[0] = -(*(volatile float*)lossacc) / (float)S_DIM;
        }
    }
}

extern "C" void kernel_launch(void* const* d_in, const int* in_sizes, int n_in,
                              void* d_out, int out_size, void* d_ws, size_t ws_size,
                              hipStream_t stream) {
    const float* z = (const float*)d_in[0];
    float* out = (float*)d_out;
    char* ws = (char*)d_ws;

    unsigned int* znb  = (unsigned int*)ws;                       // 2 MB bf16 fragment-major
    float* y0          = (float*)(ws + (2 << 20));                // 32 KB y buffers x3
    float* y1          = (float*)(ws + (2 << 20) + 65536);
    float* y2          = (float*)(ws + (2 << 20) + 131072);
    unsigned int* mins = (unsigned int*)(ws + (2 << 20) + 196608);
    float* lossacc     = (float*)(ws + (2 << 20) + 196608 + 64);
    unsigned int* cnt  = (unsigned int*)(ws + (2 << 20) + 196608 + 128);
    unsigned char* K8  = (unsigned char*)(ws + (8 << 20));        // 64 MB fp8 K' triangle

    float* ybuf[3] = {y0, y1, y2};

    normalize_kernel<<<S_DIM / 4, 256, 0, stream>>>(z, znb, y0, y1, mins, lossacc, cnt);
    gemm_exp_mfma<<<NTRI256, 512, 0, stream>>>((const short*)znb, K8, mins, lossacc);

    // pass p: x = 1/ybuf[(p-1)%3]; accumulate ybuf[p%3]; zero ybuf[(p+1)%3]
    for (int p = 1; p <= 11; ++p)
        sink_pass_kernel<<<NWORK2, 256, 0, stream>>>(K8, ybuf[(p - 1) % 3], ybuf[p % 3],
                                                     ybuf[(p + 1) % 3], mins);

    // y10 = ybuf[10%3]=y1, y11 = ybuf[11%3]=y2
    loss_kernel<<<S_DIM / 256, 256, 0, stream>>>(y2, y1, lossacc, cnt, out);
}

// Round 16
// 137.247 us; speedup vs baseline: 2.6398x; 2.6398x over previous
//
#include <hip/hip_runtime.h>

#define S_DIM 8192
#define NTRI 2080
#define NWORK2 1088   // half-row sink work blocks: 2 x sum_R (floor(R/4)+1)

typedef __attribute__((ext_vector_type(8))) short short8v;
typedef __attribute__((ext_vector_type(16))) float f32x16;
typedef __attribute__((ext_vector_type(2))) float f32x2;

__device__ inline unsigned short f32_to_bf16(float f) {
    unsigned int b = __builtin_bit_cast(unsigned int, f);
    unsigned int lsb = (b >> 16) & 1u;
    b += 0x7fffu + lsb;
    return (unsigned short)(b >> 16);
}
__device__ inline unsigned int fkey(float f) {
    unsigned int b = __builtin_bit_cast(unsigned int, f);
    return (b & 0x80000000u) ? ~b : (b | 0x80000000u);
}
__device__ inline float fkey_inv(unsigned int k) {
    unsigned int b = (k & 0x80000000u) ? (k & 0x7FFFFFFFu) : ~k;
    return __builtin_bit_cast(float, b);
}

// ---- fp8 e4m3fn helpers (values all positive) ----
__device__ inline unsigned int f32_to_fp8_scalar(float f) {
#if __has_builtin(__builtin_amdgcn_cvt_pk_fp8_f32)
    return (unsigned int)__builtin_amdgcn_cvt_pk_fp8_f32(f, f, 0, false) & 0xFFu;
#else
    if (f < 0.015625f) return (unsigned int)__float2int_rn(f * 512.0f);
    unsigned int b = __builtin_bit_cast(unsigned int, f);
    unsigned int r = b + 0x7FFFFu + ((b >> 20) & 1u);
    return (r >> 20) - 960u;
#endif
}
__device__ inline unsigned int pack_fp8x4(float a, float b, float c, float d) {
#if __has_builtin(__builtin_amdgcn_cvt_pk_fp8_f32)
    int w = __builtin_amdgcn_cvt_pk_fp8_f32(a, b, 0, false);
    w = __builtin_amdgcn_cvt_pk_fp8_f32(c, d, w, true);
    return (unsigned int)w;
#else
    return f32_to_fp8_scalar(a) | (f32_to_fp8_scalar(b) << 8) |
           (f32_to_fp8_scalar(c) << 16) | (f32_to_fp8_scalar(d) << 24);
#endif
}
#if !__has_builtin(__builtin_amdgcn_cvt_pk_f32_fp8)
__device__ inline float fp8_byte_to_f32(unsigned int u) {
    unsigned int e = (u >> 3) & 15u, m = u & 7u;
    if (e == 0) return (float)m * 0x1p-9f;
    return __builtin_bit_cast(float, ((e + 120u) << 23) | (m << 20));
}
#endif
__device__ inline void fp8x4_to_f32(unsigned int d, float* o) {
#if __has_builtin(__builtin_amdgcn_cvt_pk_f32_fp8)
    f32x2 lo = __builtin_amdgcn_cvt_pk_f32_fp8((int)d, false);
    f32x2 hi = __builtin_amdgcn_cvt_pk_f32_fp8((int)d, true);
    o[0] = lo[0]; o[1] = lo[1]; o[2] = hi[0]; o[3] = hi[1];
#else
    o[0] = fp8_byte_to_f32(d & 0xFFu);
    o[1] = fp8_byte_to_f32((d >> 8) & 0xFFu);
    o[2] = fp8_byte_to_f32((d >> 16) & 0xFFu);
    o[3] = fp8_byte_to_f32((d >> 24) & 0xFFu);
#endif
}

// triangle enumeration: id -> (bi <= bj)
__device__ inline void tri_map(int id, int& bi, int& bj) {
    int j = (int)((sqrtf(8.0f * (float)id + 1.0f) - 1.0f) * 0.5f);
    while ((j + 1) * (j + 2) / 2 <= id) ++j;
    while (j * (j + 1) / 2 > id) --j;
    bj = j;
    bi = id - j * (j + 1) / 2;
}
// sink work enumeration: id in [0,544) -> (R, s) with 4s <= R.
__device__ inline void work_map(int id, int& R, int& s) {
    int g = (int)((sqrtf(1.0f + 2.0f * (float)id) - 1.0f) * 0.5f);
    while (2 * (g + 1) * (g + 2) <= id) ++g;
    while (2 * g * (g + 1) > id) --g;
    int rem = id - 2 * g * (g + 1);
    int r = rem / (g + 1);
    s = rem - r * (g + 1);
    R = 4 * g + r;
}

// 4 rows per 256-thread block (wave per row): L2-normalize -> bf16 fragment-major
__global__ __launch_bounds__(256) void normalize_kernel(const float* __restrict__ z,
                                                        unsigned int* __restrict__ znb,
                                                        float* __restrict__ y0,
                                                        float* __restrict__ y1,
                                                        unsigned int* __restrict__ minslot,
                                                        float* __restrict__ lossacc,
                                                        unsigned int* __restrict__ cnt) {
    int t = threadIdx.x;
    int w = t >> 6, lane = t & 63;
    int row = blockIdx.x * 4 + w;
    float2 val = ((const float2*)(z + (size_t)row * 128))[lane];
    float ss = val.x * val.x + val.y * val.y;
    #pragma unroll
    for (int off = 32; off; off >>= 1) ss += __shfl_xor(ss, off);
    float inv = 1.0f / sqrtf(ss);
    float2 o; o.x = val.x * inv; o.y = val.y * inv;
    unsigned int pk = (unsigned int)f32_to_bf16(o.x) | ((unsigned int)f32_to_bf16(o.y) << 16);
    // fragment-major: granule(row,chunk) = (row>>5)*512 + chunk*32 + (row&31)
    znb[((row >> 5) * 512 + (lane >> 2) * 32 + (row & 31)) * 4 + (lane & 3)] = pk;
    if (lane == 0) {
        y0[row] = 1.0f;
        y1[row] = 0.0f;
    }
    if (blockIdx.x == 0 && t == 0) { *minslot = 0xFFFFFFFFu; *lossacc = 0.0f; *cnt = 0u; }
}

// Triangle GEMM, 8 waves x (32x64 wave tile) = 128x128 block tile.
// R16: A/B row-panels (32 KB each, contiguous in fragment-major layout) staged into
// LDS once per block; K-loop fragments come from conflict-free ds_read_b128 instead
// of 24 serialized L2 gathers per wave. Panels union'd with the Tl transpose buffer
// (dead by epilogue) -> 64 KB LDS, 2 blocks/CU. acc = 32 regs, no spill.
// Pair-loss folded for tiles with bj-bi==32; diag stored 0 (exact fix in sink pass).
__global__ __launch_bounds__(512, 4) void gemm_exp_mfma(const short* __restrict__ znb,
                                                        unsigned char* __restrict__ K8,
                                                        unsigned int* __restrict__ minslot,
                                                        float* __restrict__ lossacc) {
    __shared__ union ShU {
        struct { uint4 A[2048]; uint4 B[2048]; } p;   // 32 KB + 32 KB panels
        unsigned int Tl[128 * 32];                    // 16 KB transpose buffer
    } sh;
    __shared__ float wmins[8];
    int bi, bj;
    tri_map(blockIdx.x, bi, bj);
    const bool pairblk = (bj - bi == 32);
    const bool diagblk = (bi == bj);
    const int t = threadIdx.x;
    const int lane = t & 63, w = t >> 6;     // 8 waves
    const int tr = w >> 1, tc = w & 1;       // wave tile: rows tr*32, cols tc*64
    const int cl = lane & 31, hi = lane >> 5;

    // ---- stage A/B panels: fragment-major rows [bi*128,+128) are 2048 contiguous granules
    {
        const uint4* Zg = (const uint4*)znb;
        #pragma unroll
        for (int i = 0; i < 4; ++i)
            sh.p.A[t + i * 512] = Zg[bi * 2048 + t + i * 512];
        #pragma unroll
        for (int i = 0; i < 4; ++i)
            sh.p.B[t + i * 512] = Zg[bj * 2048 + t + i * 512];
    }
    __syncthreads();

    f32x16 acc[2];
    #pragma unroll
    for (int tj = 0; tj < 2; ++tj)
        #pragma unroll
        for (int e = 0; e < 16; ++e) acc[tj][e] = 0.0f;

    const short8v* Al = (const short8v*)sh.p.A;
    const short8v* Bl = (const short8v*)sh.p.B;
    #pragma unroll
    for (int step = 0; step < 8; ++step) {
        const int chunk = step * 2 + hi;
        short8v af = Al[tr * 512 + chunk * 32 + cl];
        short8v bf[2];
        #pragma unroll
        for (int tj = 0; tj < 2; ++tj)
            bf[tj] = Bl[(tc * 2 + tj) * 512 + chunk * 32 + cl];
        #pragma unroll
        for (int tj = 0; tj < 2; ++tj)
            acc[tj] = __builtin_amdgcn_mfma_f32_32x32x16_bf16(af, bf[tj], acc[tj], 0, 0, 0);
    }
    __syncthreads();   // panels dead; Tl aliases them

    // C layout: col = lane&31, row = (reg&3) + 8*(reg>>2) + 4*(lane>>5)
    float mn = 3.0e38f;
    float pl = 0.0f;
    const int rowA = bi * 128 + tr * 32;
    #pragma unroll
    for (int tj = 0; tj < 2; ++tj) {
        int colL = tc * 64 + tj * 32 + cl;
        int colG = bj * 128 + colL;
        int gswz = ((colL & 15) << 1) | ((colL >> 3) & 1);
        #pragma unroll
        for (int g = 0; g < 4; ++g) {
            int rowG = rowA + 8 * g + 4 * hi;
            float ev[4];
            #pragma unroll
            for (int kk = 0; kk < 4; ++kk) {
                float c = acc[tj][g * 4 + kk];
                mn = fminf(mn, c);
                if (pairblk && (colG - rowG - kk) == 4096) pl += 20.0f * (c - 1.0f);
                ev[kk] = __expf(10.0f * fminf(c, 0.6f));
            }
            if (diagblk) {
                #pragma unroll
                for (int kk = 0; kk < 4; ++kk)
                    if (rowG + kk == colG) ev[kk] = 0.0f;
            }
            unsigned int wv = pack_fp8x4(ev[0], ev[1], ev[2], ev[3]);
            int r4b = tr * 8 + 2 * g + hi;   // row-group-of-4 index, 0..31
            sh.Tl[colL * 32 + (r4b ^ gswz)] = wv;
        }
    }
    #pragma unroll
    for (int off = 32; off; off >>= 1) mn = fminf(mn, __shfl_xor(mn, off));
    if (lane == 0) wmins[w] = mn;
    if (pairblk) {
        #pragma unroll
        for (int off = 32; off; off >>= 1) pl += __shfl_xor(pl, off);
        if (lane == 0) atomicAdd(lossacc, pl);
    }
    __syncthreads();
    if (t == 0) {
        float bmin = wmins[0];
        #pragma unroll
        for (int k = 1; k < 8; ++k) bmin = fminf(bmin, wmins[k]);
        atomicMin(minslot, fkey(bmin));
    }

    // coalesced store of transposed tile at lower-triangle block (bj, bi)
    const size_t gbase = (size_t)(bj * 128) * S_DIM + (size_t)bi * 128;
    #pragma unroll
    for (int it = 0; it < 2; ++it) {
        int c = it * 64 + (t >> 3);          // 0..127
        int dq = (t & 7) * 4;
        int g2 = ((c & 15) << 1) | ((c >> 3) & 1);
        uint4 wv;
        wv.x = sh.Tl[c * 32 + ((dq + 0) ^ g2)];
        wv.y = sh.Tl[c * 32 + ((dq + 1) ^ g2)];
        wv.z = sh.Tl[c * 32 + ((dq + 2) ^ g2)];
        wv.w = sh.Tl[c * 32 + ((dq + 3) ^ g2)];
        *(uint4*)(K8 + gbase + (size_t)c * S_DIM + dq * 4) = wv;
    }
}

// One Sinkhorn pass, 1088 half-row work blocks (R12-proven, byte-identical).
__global__ __launch_bounds__(256, 4) void sink_pass_kernel(const unsigned char* __restrict__ K8,
                                                           const float* __restrict__ yprev,
                                                           float* __restrict__ ycur,
                                                           float* __restrict__ ynext,
                                                           const unsigned int* __restrict__ minslot) {
    __shared__ float xsc[512];
    __shared__ float xsr[64];
    __shared__ float rdp[64 * 33];
    __shared__ float csum[4 * 512];
    const int t = threadIdx.x;
    const int id = blockIdx.x;
    if (id < 32) ynext[id * 256 + t] = 0.0f;

    int R, s;
    work_map(id >> 1, R, s);
    const int h = id & 1;
    const int q0 = s * 4;
    const int rbase = R * 128 + h * 64;
    if (t < 64) xsr[t] = 1.0f / yprev[rbase + t];
    xsc[t]       = 1.0f / yprev[q0 * 128 + t];
    xsc[t + 256] = 1.0f / yprev[q0 * 128 + 256 + t];

    const int w = t >> 6, lane = t & 63, half = lane >> 5, d = lane & 31;
    const int C = q0 + (d >> 3);
    const bool tvalid = (C <= R);
    const bool cvalid = (C < R);

    uint4 kreg[8];
    const unsigned char* base = K8 + (size_t)(rbase + (w << 4) + half) * S_DIM
                                   + q0 * 128 + d * 16;
    if (tvalid) {
        #pragma unroll
        for (int i2 = 0; i2 < 8; ++i2)
            kreg[i2] = *(const uint4*)(base + (size_t)(i2 << 1) * S_DIM);
    } else {
        #pragma unroll
        for (int i2 = 0; i2 < 8; ++i2) kreg[i2] = (uint4){0u, 0u, 0u, 0u};
    }
    __syncthreads();

    float xr[16];
    #pragma unroll
    for (int u = 0; u < 4; ++u)
        *(float4*)&xr[u * 4] = *(const float4*)&xsc[d * 16 + u * 4];
    float ca[16];
    #pragma unroll
    for (int e = 0; e < 16; ++e) ca[e] = 0.0f;

    #pragma unroll
    for (int i2 = 0; i2 < 8; ++i2) {
        int row = (w << 4) + (i2 << 1) + half;
        float f[16];
        fp8x4_to_f32(kreg[i2].x, f + 0);  fp8x4_to_f32(kreg[i2].y, f + 4);
        fp8x4_to_f32(kreg[i2].z, f + 8);  fp8x4_to_f32(kreg[i2].w, f + 12);
        float rd = 0.0f;
        #pragma unroll
        for (int e = 0; e < 16; ++e) rd += f[e] * xr[e];
        if (cvalid) {
            float xv = xsr[row];
            #pragma unroll
            for (int e = 0; e < 16; ++e) ca[e] += f[e] * xv;
        }
        rdp[row * 33 + d] = rd;
    }
    #pragma unroll
    for (int e = 0; e < 16; ++e) ca[e] += __shfl_xor(ca[e], 32);
    if (half == 0) {
        #pragma unroll
        for (int u = 0; u < 4; ++u) {
            float4 v; v.x = ca[u*4]; v.y = ca[u*4+1]; v.z = ca[u*4+2]; v.w = ca[u*4+3];
            *(float4*)&csum[w * 512 + d * 16 + u * 4] = v;
        }
    }
    __syncthreads();
    if (t < 64) {
        float sum = 0.0f;
        #pragma unroll
        for (int k = 0; k < 32; ++k) sum += rdp[t * 33 + k];
        if (s == (R >> 2))
            sum += __expf(10.0f * fkey_inv(*minslot)) * xsr[t];
        atomicAdd(&ycur[rbase + t], sum);
    }
    #pragma unroll
    for (int u = 0; u < 2; ++u) {
        int cc = t + u * 256;
        int Cc = q0 + (cc >> 7);
        if (Cc < R)
            atomicAdd(&ycur[q0 * 128 + cc],
                      csum[cc] + csum[512 + cc] + csum[1024 + cc] + csum[1536 + cc]);
    }
}

// Final loss: pair term already in lossacc; add sum_i (10 - log y11[i] - log y10[i]).
__global__ __launch_bounds__(256) void loss_kernel(const float* __restrict__ y11,
                                                   const float* __restrict__ y10,
                                                   float* __restrict__ lossacc,
                                                   unsigned int* __restrict__ cnt,
                                                   float* __restrict__ out) {
    __shared__ float wpart[4];
    const int t = threadIdx.x;
    int i = blockIdx.x * 256 + t;
    float val = 10.0f - __logf(y11[i]) - __logf(y10[i]);
    #pragma unroll
    for (int off = 32; off; off >>= 1) val += __shfl_xor(val, off);
    if ((t & 63) == 0) wpart[t >> 6] = val;
    __syncthreads();
    if (t == 0) {
        atomicAdd(lossacc, wpart[0] + wpart[1] + wpart[2] + wpart[3]);
        __threadfence();
        unsigned int done = atomicAdd(cnt, 1u);
        if (done == gridDim.x - 1) {
            __threadfence();
            out[0] = -(*(volatile float*)lossacc) / (float)S_DIM;
        }
    }
}

extern "C" void kernel_launch(void* const* d_in, const int* in_sizes, int n_in,
                              void* d_out, int out_size, void* d_ws, size_t ws_size,
                              hipStream_t stream) {
    const float* z = (const float*)d_in[0];
    float* out = (float*)d_out;
    char* ws = (char*)d_ws;

    unsigned int* znb  = (unsigned int*)ws;                       // 2 MB bf16 fragment-major
    float* y0          = (float*)(ws + (2 << 20));                // 32 KB y buffers x3
    float* y1          = (float*)(ws + (2 << 20) + 65536);
    float* y2          = (float*)(ws + (2 << 20) + 131072);
    unsigned int* mins = (unsigned int*)(ws + (2 << 20) + 196608);
    float* lossacc     = (float*)(ws + (2 << 20) + 196608 + 64);
    unsigned int* cnt  = (unsigned int*)(ws + (2 << 20) + 196608 + 128);
    unsigned char* K8  = (unsigned char*)(ws + (8 << 20));        // 64 MB fp8 K' triangle

    float* ybuf[3] = {y0, y1, y2};

    normalize_kernel<<<S_DIM / 4, 256, 0, stream>>>(z, znb, y0, y1, mins, lossacc, cnt);
    gemm_exp_mfma<<<NTRI, 512, 0, stream>>>((const short*)znb, K8, mins, lossacc);

    // pass p: x = 1/ybuf[(p-1)%3]; accumulate ybuf[p%3]; zero ybuf[(p+1)%3]
    for (int p = 1; p <= 11; ++p)
        sink_pass_kernel<<<NWORK2, 256, 0, stream>>>(K8, ybuf[(p - 1) % 3], ybuf[p % 3],
                                                     ybuf[(p + 1) % 3], mins);

    // y10 = ybuf[10%3]=y1, y11 = ybuf[11%3]=y2
    loss_kernel<<<S_DIM / 256, 256, 0, stream>>>(y2, y1, lossacc, cnt, out);
}

// Round 17
// 125.552 us; speedup vs baseline: 2.8857x; 1.0932x over previous
//
#include <hip/hip_runtime.h>

#define S_DIM 8192
#define NTRI 2080
#define NWORK2 1088   // half-row sink work blocks: 2 x sum_R (floor(R/4)+1)

typedef __attribute__((ext_vector_type(8))) short short8v;
typedef __attribute__((ext_vector_type(16))) float f32x16;
typedef __attribute__((ext_vector_type(2))) float f32x2;

__device__ inline unsigned short f32_to_bf16(float f) {
    unsigned int b = __builtin_bit_cast(unsigned int, f);
    unsigned int lsb = (b >> 16) & 1u;
    b += 0x7fffu + lsb;
    return (unsigned short)(b >> 16);
}
__device__ inline unsigned int fkey(float f) {
    unsigned int b = __builtin_bit_cast(unsigned int, f);
    return (b & 0x80000000u) ? ~b : (b | 0x80000000u);
}
__device__ inline float fkey_inv(unsigned int k) {
    unsigned int b = (k & 0x80000000u) ? (k & 0x7FFFFFFFu) : ~k;
    return __builtin_bit_cast(float, b);
}

// ---- fp8 e4m3fn helpers (values all positive) ----
__device__ inline unsigned int f32_to_fp8_scalar(float f) {
#if __has_builtin(__builtin_amdgcn_cvt_pk_fp8_f32)
    return (unsigned int)__builtin_amdgcn_cvt_pk_fp8_f32(f, f, 0, false) & 0xFFu;
#else
    if (f < 0.015625f) return (unsigned int)__float2int_rn(f * 512.0f);
    unsigned int b = __builtin_bit_cast(unsigned int, f);
    unsigned int r = b + 0x7FFFFu + ((b >> 20) & 1u);
    return (r >> 20) - 960u;
#endif
}
__device__ inline unsigned int pack_fp8x4(float a, float b, float c, float d) {
#if __has_builtin(__builtin_amdgcn_cvt_pk_fp8_f32)
    int w = __builtin_amdgcn_cvt_pk_fp8_f32(a, b, 0, false);
    w = __builtin_amdgcn_cvt_pk_fp8_f32(c, d, w, true);
    return (unsigned int)w;
#else
    return f32_to_fp8_scalar(a) | (f32_to_fp8_scalar(b) << 8) |
           (f32_to_fp8_scalar(c) << 16) | (f32_to_fp8_scalar(d) << 24);
#endif
}
#if !__has_builtin(__builtin_amdgcn_cvt_pk_f32_fp8)
__device__ inline float fp8_byte_to_f32(unsigned int u) {
    unsigned int e = (u >> 3) & 15u, m = u & 7u;
    if (e == 0) return (float)m * 0x1p-9f;
    return __builtin_bit_cast(float, ((e + 120u) << 23) | (m << 20));
}
#endif
__device__ inline void fp8x4_to_f32(unsigned int d, float* o) {
#if __has_builtin(__builtin_amdgcn_cvt_pk_f32_fp8)
    f32x2 lo = __builtin_amdgcn_cvt_pk_f32_fp8((int)d, false);
    f32x2 hi = __builtin_amdgcn_cvt_pk_f32_fp8((int)d, true);
    o[0] = lo[0]; o[1] = lo[1]; o[2] = hi[0]; o[3] = hi[1];
#else
    o[0] = fp8_byte_to_f32(d & 0xFFu);
    o[1] = fp8_byte_to_f32((d >> 8) & 0xFFu);
    o[2] = fp8_byte_to_f32((d >> 16) & 0xFFu);
    o[3] = fp8_byte_to_f32((d >> 24) & 0xFFu);
#endif
}

// triangle enumeration: id -> (bi <= bj)
__device__ inline void tri_map(int id, int& bi, int& bj) {
    int j = (int)((sqrtf(8.0f * (float)id + 1.0f) - 1.0f) * 0.5f);
    while ((j + 1) * (j + 2) / 2 <= id) ++j;
    while (j * (j + 1) / 2 > id) --j;
    bj = j;
    bi = id - j * (j + 1) / 2;
}
// sink work enumeration: id in [0,544) -> (R, s) with 4s <= R.
__device__ inline void work_map(int id, int& R, int& s) {
    int g = (int)((sqrtf(1.0f + 2.0f * (float)id) - 1.0f) * 0.5f);
    while (2 * (g + 1) * (g + 2) <= id) ++g;
    while (2 * g * (g + 1) > id) --g;
    int rem = id - 2 * g * (g + 1);
    int r = rem / (g + 1);
    s = rem - r * (g + 1);
    R = 4 * g + r;
}

// 4 rows per 256-thread block (wave per row): L2-normalize -> bf16 fragment-major
__global__ __launch_bounds__(256) void normalize_kernel(const float* __restrict__ z,
                                                        unsigned int* __restrict__ znb,
                                                        float* __restrict__ y0,
                                                        float* __restrict__ y1,
                                                        unsigned int* __restrict__ minslot,
                                                        float* __restrict__ lossacc,
                                                        unsigned int* __restrict__ cnt) {
    int t = threadIdx.x;
    int w = t >> 6, lane = t & 63;
    int row = blockIdx.x * 4 + w;
    float2 val = ((const float2*)(z + (size_t)row * 128))[lane];
    float ss = val.x * val.x + val.y * val.y;
    #pragma unroll
    for (int off = 32; off; off >>= 1) ss += __shfl_xor(ss, off);
    float inv = 1.0f / sqrtf(ss);
    float2 o; o.x = val.x * inv; o.y = val.y * inv;
    unsigned int pk = (unsigned int)f32_to_bf16(o.x) | ((unsigned int)f32_to_bf16(o.y) << 16);
    // fragment-major: granule(row,chunk) = (row>>5)*512 + chunk*32 + (row&31)
    znb[((row >> 5) * 512 + (lane >> 2) * 32 + (row & 31)) * 4 + (lane & 3)] = pk;
    if (lane == 0) {
        y0[row] = 1.0f;
        y1[row] = 0.0f;
    }
    if (blockIdx.x == 0 && t == 0) { *minslot = 0xFFFFFFFFu; *lossacc = 0.0f; *cnt = 0u; }
}

// Triangle GEMM, 8 waves x (32x64 wave tile) = 128x128 block tile (R16 structure).
// R17: K8 is TILE-MAJOR — tile (R=bj, C=bi) contiguous 16 KB at (R(R+1)/2+C)*16384,
// row-major inside. The transposed store becomes one contiguous 16 KB stream/block.
__global__ __launch_bounds__(512, 4) void gemm_exp_mfma(const short* __restrict__ znb,
                                                        unsigned char* __restrict__ K8,
                                                        unsigned int* __restrict__ minslot,
                                                        float* __restrict__ lossacc) {
    __shared__ union ShU {
        struct { uint4 A[2048]; uint4 B[2048]; } p;   // 32 KB + 32 KB panels
        unsigned int Tl[128 * 32];                    // 16 KB transpose buffer
    } sh;
    __shared__ float wmins[8];
    int bi, bj;
    tri_map(blockIdx.x, bi, bj);
    const bool pairblk = (bj - bi == 32);
    const bool diagblk = (bi == bj);
    const int t = threadIdx.x;
    const int lane = t & 63, w = t >> 6;     // 8 waves
    const int tr = w >> 1, tc = w & 1;       // wave tile: rows tr*32, cols tc*64
    const int cl = lane & 31, hi = lane >> 5;

    // ---- stage A/B panels: fragment-major rows [bi*128,+128) are 2048 contiguous granules
    {
        const uint4* Zg = (const uint4*)znb;
        #pragma unroll
        for (int i = 0; i < 4; ++i)
            sh.p.A[t + i * 512] = Zg[bi * 2048 + t + i * 512];
        #pragma unroll
        for (int i = 0; i < 4; ++i)
            sh.p.B[t + i * 512] = Zg[bj * 2048 + t + i * 512];
    }
    __syncthreads();

    f32x16 acc[2];
    #pragma unroll
    for (int tj = 0; tj < 2; ++tj)
        #pragma unroll
        for (int e = 0; e < 16; ++e) acc[tj][e] = 0.0f;

    const short8v* Al = (const short8v*)sh.p.A;
    const short8v* Bl = (const short8v*)sh.p.B;
    #pragma unroll
    for (int step = 0; step < 8; ++step) {
        const int chunk = step * 2 + hi;
        short8v af = Al[tr * 512 + chunk * 32 + cl];
        short8v bf[2];
        #pragma unroll
        for (int tj = 0; tj < 2; ++tj)
            bf[tj] = Bl[(tc * 2 + tj) * 512 + chunk * 32 + cl];
        #pragma unroll
        for (int tj = 0; tj < 2; ++tj)
            acc[tj] = __builtin_amdgcn_mfma_f32_32x32x16_bf16(af, bf[tj], acc[tj], 0, 0, 0);
    }
    __syncthreads();   // panels dead; Tl aliases them

    // C layout: col = lane&31, row = (reg&3) + 8*(reg>>2) + 4*(lane>>5)
    float mn = 3.0e38f;
    float pl = 0.0f;
    const int rowA = bi * 128 + tr * 32;
    #pragma unroll
    for (int tj = 0; tj < 2; ++tj) {
        int colL = tc * 64 + tj * 32 + cl;
        int colG = bj * 128 + colL;
        int gswz = ((colL & 15) << 1) | ((colL >> 3) & 1);
        #pragma unroll
        for (int g = 0; g < 4; ++g) {
            int rowG = rowA + 8 * g + 4 * hi;
            float ev[4];
            #pragma unroll
            for (int kk = 0; kk < 4; ++kk) {
                float c = acc[tj][g * 4 + kk];
                mn = fminf(mn, c);
                if (pairblk && (colG - rowG - kk) == 4096) pl += 20.0f * (c - 1.0f);
                ev[kk] = __expf(10.0f * fminf(c, 0.6f));
            }
            if (diagblk) {
                #pragma unroll
                for (int kk = 0; kk < 4; ++kk)
                    if (rowG + kk == colG) ev[kk] = 0.0f;
            }
            unsigned int wv = pack_fp8x4(ev[0], ev[1], ev[2], ev[3]);
            int r4b = tr * 8 + 2 * g + hi;   // row-group-of-4 index, 0..31
            sh.Tl[colL * 32 + (r4b ^ gswz)] = wv;
        }
    }
    #pragma unroll
    for (int off = 32; off; off >>= 1) mn = fminf(mn, __shfl_xor(mn, off));
    if (lane == 0) wmins[w] = mn;
    if (pairblk) {
        #pragma unroll
        for (int off = 32; off; off >>= 1) pl += __shfl_xor(pl, off);
        if (lane == 0) atomicAdd(lossacc, pl);
    }
    __syncthreads();
    if (t == 0) {
        float bmin = wmins[0];
        #pragma unroll
        for (int k = 1; k < 8; ++k) bmin = fminf(bmin, wmins[k]);
        atomicMin(minslot, fkey(bmin));
    }

    // contiguous 16 KB store of transposed tile at tile-slot (R=bj, C=bi)
    unsigned char* tbase = K8 + (size_t)((bj * (bj + 1)) / 2 + bi) * 16384;
    #pragma unroll
    for (int it = 0; it < 2; ++it) {
        int c = it * 64 + (t >> 3);          // local row in stored tile, 0..127
        int dq = (t & 7) * 4;
        int g2 = ((c & 15) << 1) | ((c >> 3) & 1);
        uint4 wv;
        wv.x = sh.Tl[c * 32 + ((dq + 0) ^ g2)];
        wv.y = sh.Tl[c * 32 + ((dq + 1) ^ g2)];
        wv.z = sh.Tl[c * 32 + ((dq + 2) ^ g2)];
        wv.w = sh.Tl[c * 32 + ((dq + 3) ^ g2)];
        *(uint4*)(tbase + c * 128 + dq * 4) = wv;
    }
}

// One Sinkhorn pass, 1088 half-row work blocks (R12 structure; R17 tile-major reads).
// Block (R,s,h): reads half-tiles (rows [h*64,h*64+64)) of tiles (R, 4s..4s+3) —
// each an 8 KB contiguous stream.
__global__ __launch_bounds__(256, 4) void sink_pass_kernel(const unsigned char* __restrict__ K8,
                                                           const float* __restrict__ yprev,
                                                           float* __restrict__ ycur,
                                                           float* __restrict__ ynext,
                                                           const unsigned int* __restrict__ minslot) {
    __shared__ float xsc[512];
    __shared__ float xsr[64];
    __shared__ float rdp[64 * 33];
    __shared__ float csum[4 * 512];
    const int t = threadIdx.x;
    const int id = blockIdx.x;
    if (id < 32) ynext[id * 256 + t] = 0.0f;

    int R, s;
    work_map(id >> 1, R, s);
    const int h = id & 1;
    const int q0 = s * 4;
    const int rbase = R * 128 + h * 64;
    if (t < 64) xsr[t] = 1.0f / yprev[rbase + t];
    xsc[t]       = 1.0f / yprev[q0 * 128 + t];
    xsc[t + 256] = 1.0f / yprev[q0 * 128 + 256 + t];

    const int w = t >> 6, lane = t & 63, half = lane >> 5, d = lane & 31;
    const int ct = d >> 3;              // column tile within the 4-span
    const int C = q0 + ct;
    const bool tvalid = (C <= R);
    const bool cvalid = (C < R);

    // tile-major: tile (R,C) at (R(R+1)/2 + C)*16384, row-major 128B rows
    uint4 kreg[8];
    const unsigned char* base = K8 + (size_t)((R * (R + 1)) / 2 + C) * 16384
                                   + (h * 64 + (w << 4) + half) * 128 + (d & 7) * 16;
    if (tvalid) {
        #pragma unroll
        for (int i2 = 0; i2 < 8; ++i2)
            kreg[i2] = *(const uint4*)(base + (i2 << 1) * 128);
    } else {
        #pragma unroll
        for (int i2 = 0; i2 < 8; ++i2) kreg[i2] = (uint4){0u, 0u, 0u, 0u};
    }
    __syncthreads();

    float xr[16];
    #pragma unroll
    for (int u = 0; u < 4; ++u)
        *(float4*)&xr[u * 4] = *(const float4*)&xsc[d * 16 + u * 4];
    float ca[16];
    #pragma unroll
    for (int e = 0; e < 16; ++e) ca[e] = 0.0f;

    #pragma unroll
    for (int i2 = 0; i2 < 8; ++i2) {
        int row = (w << 4) + (i2 << 1) + half;
        float f[16];
        fp8x4_to_f32(kreg[i2].x, f + 0);  fp8x4_to_f32(kreg[i2].y, f + 4);
        fp8x4_to_f32(kreg[i2].z, f + 8);  fp8x4_to_f32(kreg[i2].w, f + 12);
        float rd = 0.0f;
        #pragma unroll
        for (int e = 0; e < 16; ++e) rd += f[e] * xr[e];
        if (cvalid) {
            float xv = xsr[row];
            #pragma unroll
            for (int e = 0; e < 16; ++e) ca[e] += f[e] * xv;
        }
        rdp[row * 33 + d] = rd;
    }
    #pragma unroll
    for (int e = 0; e < 16; ++e) ca[e] += __shfl_xor(ca[e], 32);
    if (half == 0) {
        #pragma unroll
        for (int u = 0; u < 4; ++u) {
            float4 v; v.x = ca[u*4]; v.y = ca[u*4+1]; v.z = ca[u*4+2]; v.w = ca[u*4+3];
            *(float4*)&csum[w * 512 + d * 16 + u * 4] = v;
        }
    }
    __syncthreads();
    if (t < 64) {
        float sum = 0.0f;
        #pragma unroll
        for (int k = 0; k < 32; ++k) sum += rdp[t * 33 + k];
        if (s == (R >> 2))
            sum += __expf(10.0f * fkey_inv(*minslot)) * xsr[t];
        atomicAdd(&ycur[rbase + t], sum);
    }
    #pragma unroll
    for (int u = 0; u < 2; ++u) {
        int cc = t + u * 256;
        int Cc = q0 + (cc >> 7);
        if (Cc < R)
            atomicAdd(&ycur[q0 * 128 + cc],
                      csum[cc] + csum[512 + cc] + csum[1024 + cc] + csum[1536 + cc]);
    }
}

// Final loss: pair term already in lossacc; add sum_i (10 - log y11[i] - log y10[i]).
__global__ __launch_bounds__(256) void loss_kernel(const float* __restrict__ y11,
                                                   const float* __restrict__ y10,
                                                   float* __restrict__ lossacc,
                                                   unsigned int* __restrict__ cnt,
                                                   float* __restrict__ out) {
    __shared__ float wpart[4];
    const int t = threadIdx.x;
    int i = blockIdx.x * 256 + t;
    float val = 10.0f - __logf(y11[i]) - __logf(y10[i]);
    #pragma unroll
    for (int off = 32; off; off >>= 1) val += __shfl_xor(val, off);
    if ((t & 63) == 0) wpart[t >> 6] = val;
    __syncthreads();
    if (t == 0) {
        atomicAdd(lossacc, wpart[0] + wpart[1] + wpart[2] + wpart[3]);
        __threadfence();
        unsigned int done = atomicAdd(cnt, 1u);
        if (done == gridDim.x - 1) {
            __threadfence();
            out[0] = -(*(volatile float*)lossacc) / (float)S_DIM;
        }
    }
}

extern "C" void kernel_launch(void* const* d_in, const int* in_sizes, int n_in,
                              void* d_out, int out_size, void* d_ws, size_t ws_size,
                              hipStream_t stream) {
    const float* z = (const float*)d_in[0];
    float* out = (float*)d_out;
    char* ws = (char*)d_ws;

    unsigned int* znb  = (unsigned int*)ws;                       // 2 MB bf16 fragment-major
    float* y0          = (float*)(ws + (2 << 20));                // 32 KB y buffers x3
    float* y1          = (float*)(ws + (2 << 20) + 65536);
    float* y2          = (float*)(ws + (2 << 20) + 131072);
    unsigned int* mins = (unsigned int*)(ws + (2 << 20) + 196608);
    float* lossacc     = (float*)(ws + (2 << 20) + 196608 + 64);
    unsigned int* cnt  = (unsigned int*)(ws + (2 << 20) + 196608 + 128);
    unsigned char* K8  = (unsigned char*)(ws + (8 << 20));        // 34 MB fp8 K' tile-major

    float* ybuf[3] = {y0, y1, y2};

    normalize_kernel<<<S_DIM / 4, 256, 0, stream>>>(z, znb, y0, y1, mins, lossacc, cnt);
    gemm_exp_mfma<<<NTRI, 512, 0, stream>>>((const short*)znb, K8, mins, lossacc);

    // pass p: x = 1/ybuf[(p-1)%3]; accumulate ybuf[p%3]; zero ybuf[(p+1)%3]
    for (int p = 1; p <= 11; ++p)
        sink_pass_kernel<<<NWORK2, 256, 0, stream>>>(K8, ybuf[(p - 1) % 3], ybuf[p % 3],
                                                     ybuf[(p + 1) % 3], mins);

    // y10 = ybuf[10%3]=y1, y11 = ybuf[11%3]=y2
    loss_kernel<<<S_DIM / 256, 256, 0, stream>>>(y2, y1, lossacc, cnt, out);
}

// Round 18
// 125.503 us; speedup vs baseline: 2.8868x; 1.0004x over previous
//
#include <hip/hip_runtime.h>

#define S_DIM 8192
#define NTRI 2080
#define NWORK2 1088   // half-row sink work blocks: 2 x sum_R (floor(R/4)+1)

typedef __attribute__((ext_vector_type(8))) short short8v;
typedef __attribute__((ext_vector_type(16))) float f32x16;
typedef __attribute__((ext_vector_type(2))) float f32x2;

__device__ inline unsigned short f32_to_bf16(float f) {
    unsigned int b = __builtin_bit_cast(unsigned int, f);
    unsigned int lsb = (b >> 16) & 1u;
    b += 0x7fffu + lsb;
    return (unsigned short)(b >> 16);
}
__device__ inline unsigned int fkey(float f) {
    unsigned int b = __builtin_bit_cast(unsigned int, f);
    return (b & 0x80000000u) ? ~b : (b | 0x80000000u);
}
__device__ inline float fkey_inv(unsigned int k) {
    unsigned int b = (k & 0x80000000u) ? (k & 0x7FFFFFFFu) : ~k;
    return __builtin_bit_cast(float, b);
}

// ---- fp8 e4m3fn helpers (values all positive) ----
__device__ inline unsigned int f32_to_fp8_scalar(float f) {
#if __has_builtin(__builtin_amdgcn_cvt_pk_fp8_f32)
    return (unsigned int)__builtin_amdgcn_cvt_pk_fp8_f32(f, f, 0, false) & 0xFFu;
#else
    if (f < 0.015625f) return (unsigned int)__float2int_rn(f * 512.0f);
    unsigned int b = __builtin_bit_cast(unsigned int, f);
    unsigned int r = b + 0x7FFFFu + ((b >> 20) & 1u);
    return (r >> 20) - 960u;
#endif
}
__device__ inline unsigned int pack_fp8x4(float a, float b, float c, float d) {
#if __has_builtin(__builtin_amdgcn_cvt_pk_fp8_f32)
    int w = __builtin_amdgcn_cvt_pk_fp8_f32(a, b, 0, false);
    w = __builtin_amdgcn_cvt_pk_fp8_f32(c, d, w, true);
    return (unsigned int)w;
#else
    return f32_to_fp8_scalar(a) | (f32_to_fp8_scalar(b) << 8) |
           (f32_to_fp8_scalar(c) << 16) | (f32_to_fp8_scalar(d) << 24);
#endif
}
#if !__has_builtin(__builtin_amdgcn_cvt_pk_f32_fp8)
__device__ inline float fp8_byte_to_f32(unsigned int u) {
    unsigned int e = (u >> 3) & 15u, m = u & 7u;
    if (e == 0) return (float)m * 0x1p-9f;
    return __builtin_bit_cast(float, ((e + 120u) << 23) | (m << 20));
}
#endif
__device__ inline void fp8x4_to_f32(unsigned int d, float* o) {
#if __has_builtin(__builtin_amdgcn_cvt_pk_f32_fp8)
    f32x2 lo = __builtin_amdgcn_cvt_pk_f32_fp8((int)d, false);
    f32x2 hi = __builtin_amdgcn_cvt_pk_f32_fp8((int)d, true);
    o[0] = lo[0]; o[1] = lo[1]; o[2] = hi[0]; o[3] = hi[1];
#else
    o[0] = fp8_byte_to_f32(d & 0xFFu);
    o[1] = fp8_byte_to_f32((d >> 8) & 0xFFu);
    o[2] = fp8_byte_to_f32((d >> 16) & 0xFFu);
    o[3] = fp8_byte_to_f32((d >> 24) & 0xFFu);
#endif
}

// triangle enumeration: id -> (bi <= bj)
__device__ inline void tri_map(int id, int& bi, int& bj) {
    int j = (int)((sqrtf(8.0f * (float)id + 1.0f) - 1.0f) * 0.5f);
    while ((j + 1) * (j + 2) / 2 <= id) ++j;
    while (j * (j + 1) / 2 > id) --j;
    bj = j;
    bi = id - j * (j + 1) / 2;
}

// XCD-affine sink work map: physical block b (XCD = b%8, round-robin) -> logical
// (R, s, h) with R%8 == b%8 (except 32 overflow works, 3%). Tile (R,C) is read only
// by blocks with that R -> per-XCD read set 3.6-4.5 MB, L2-resident across passes.
// Group x sizes: 128+16*(x>>2); physical slots/group: 136. Idle slots of x<4 take
// the 8 overflow works of group x+4.
__device__ inline void sink_map(int b, int& R, int& s, int& h) {
    int x = b & 7, j = b >> 3;            // j in [0,136)
    if (x < 4 && j >= 128) {              // idle slot -> overflow work of group x+4
        x += 4;
        j = 136 + (j - 128);              // 136..143
    }
    int m = 0;
    #pragma unroll
    for (int mm = 0; mm < 8; ++mm) {
        int cm = 2 * (2 * mm + (x >> 2) + 1);   // works for R = 8*mm + x
        if (j >= cm) { j -= cm; m = mm + 1; }
    }
    R = 8 * m + x;
    s = j >> 1;
    h = j & 1;
}

// 4 rows per 256-thread block (wave per row): L2-normalize -> bf16 fragment-major
__global__ __launch_bounds__(256) void normalize_kernel(const float* __restrict__ z,
                                                        unsigned int* __restrict__ znb,
                                                        float* __restrict__ y0,
                                                        float* __restrict__ y1,
                                                        unsigned int* __restrict__ minslot,
                                                        float* __restrict__ lossacc,
                                                        unsigned int* __restrict__ cnt) {
    int t = threadIdx.x;
    int w = t >> 6, lane = t & 63;
    int row = blockIdx.x * 4 + w;
    float2 val = ((const float2*)(z + (size_t)row * 128))[lane];
    float ss = val.x * val.x + val.y * val.y;
    #pragma unroll
    for (int off = 32; off; off >>= 1) ss += __shfl_xor(ss, off);
    float inv = 1.0f / sqrtf(ss);
    float2 o; o.x = val.x * inv; o.y = val.y * inv;
    unsigned int pk = (unsigned int)f32_to_bf16(o.x) | ((unsigned int)f32_to_bf16(o.y) << 16);
    // fragment-major: granule(row,chunk) = (row>>5)*512 + chunk*32 + (row&31)
    znb[((row >> 5) * 512 + (lane >> 2) * 32 + (row & 31)) * 4 + (lane & 3)] = pk;
    if (lane == 0) {
        y0[row] = 1.0f;
        y1[row] = 0.0f;
    }
    if (blockIdx.x == 0 && t == 0) { *minslot = 0xFFFFFFFFu; *lossacc = 0.0f; *cnt = 0u; }
}

// Triangle GEMM, 8 waves x (32x64 wave tile) = 128x128 block tile (R17-proven).
// K8 tile-major: tile (R=bj, C=bi) contiguous 16 KB at (R(R+1)/2+C)*16384.
__global__ __launch_bounds__(512, 4) void gemm_exp_mfma(const short* __restrict__ znb,
                                                        unsigned char* __restrict__ K8,
                                                        unsigned int* __restrict__ minslot,
                                                        float* __restrict__ lossacc) {
    __shared__ union ShU {
        struct { uint4 A[2048]; uint4 B[2048]; } p;   // 32 KB + 32 KB panels
        unsigned int Tl[128 * 32];                    // 16 KB transpose buffer
    } sh;
    __shared__ float wmins[8];
    int bi, bj;
    tri_map(blockIdx.x, bi, bj);
    const bool pairblk = (bj - bi == 32);
    const bool diagblk = (bi == bj);
    const int t = threadIdx.x;
    const int lane = t & 63, w = t >> 6;     // 8 waves
    const int tr = w >> 1, tc = w & 1;       // wave tile: rows tr*32, cols tc*64
    const int cl = lane & 31, hi = lane >> 5;

    // ---- stage A/B panels: fragment-major rows [bi*128,+128) are 2048 contiguous granules
    {
        const uint4* Zg = (const uint4*)znb;
        #pragma unroll
        for (int i = 0; i < 4; ++i)
            sh.p.A[t + i * 512] = Zg[bi * 2048 + t + i * 512];
        #pragma unroll
        for (int i = 0; i < 4; ++i)
            sh.p.B[t + i * 512] = Zg[bj * 2048 + t + i * 512];
    }
    __syncthreads();

    f32x16 acc[2];
    #pragma unroll
    for (int tj = 0; tj < 2; ++tj)
        #pragma unroll
        for (int e = 0; e < 16; ++e) acc[tj][e] = 0.0f;

    const short8v* Al = (const short8v*)sh.p.A;
    const short8v* Bl = (const short8v*)sh.p.B;
    #pragma unroll
    for (int step = 0; step < 8; ++step) {
        const int chunk = step * 2 + hi;
        short8v af = Al[tr * 512 + chunk * 32 + cl];
        short8v bf[2];
        #pragma unroll
        for (int tj = 0; tj < 2; ++tj)
            bf[tj] = Bl[(tc * 2 + tj) * 512 + chunk * 32 + cl];
        #pragma unroll
        for (int tj = 0; tj < 2; ++tj)
            acc[tj] = __builtin_amdgcn_mfma_f32_32x32x16_bf16(af, bf[tj], acc[tj], 0, 0, 0);
    }
    __syncthreads();   // panels dead; Tl aliases them

    // C layout: col = lane&31, row = (reg&3) + 8*(reg>>2) + 4*(lane>>5)
    float mn = 3.0e38f;
    float pl = 0.0f;
    const int rowA = bi * 128 + tr * 32;
    #pragma unroll
    for (int tj = 0; tj < 2; ++tj) {
        int colL = tc * 64 + tj * 32 + cl;
        int colG = bj * 128 + colL;
        int gswz = ((colL & 15) << 1) | ((colL >> 3) & 1);
        #pragma unroll
        for (int g = 0; g < 4; ++g) {
            int rowG = rowA + 8 * g + 4 * hi;
            float ev[4];
            #pragma unroll
            for (int kk = 0; kk < 4; ++kk) {
                float c = acc[tj][g * 4 + kk];
                mn = fminf(mn, c);
                if (pairblk && (colG - rowG - kk) == 4096) pl += 20.0f * (c - 1.0f);
                ev[kk] = __expf(10.0f * fminf(c, 0.6f));
            }
            if (diagblk) {
                #pragma unroll
                for (int kk = 0; kk < 4; ++kk)
                    if (rowG + kk == colG) ev[kk] = 0.0f;
            }
            unsigned int wv = pack_fp8x4(ev[0], ev[1], ev[2], ev[3]);
            int r4b = tr * 8 + 2 * g + hi;   // row-group-of-4 index, 0..31
            sh.Tl[colL * 32 + (r4b ^ gswz)] = wv;
        }
    }
    #pragma unroll
    for (int off = 32; off; off >>= 1) mn = fminf(mn, __shfl_xor(mn, off));
    if (lane == 0) wmins[w] = mn;
    if (pairblk) {
        #pragma unroll
        for (int off = 32; off; off >>= 1) pl += __shfl_xor(pl, off);
        if (lane == 0) atomicAdd(lossacc, pl);
    }
    __syncthreads();
    if (t == 0) {
        float bmin = wmins[0];
        #pragma unroll
        for (int k = 1; k < 8; ++k) bmin = fminf(bmin, wmins[k]);
        atomicMin(minslot, fkey(bmin));
    }

    // contiguous 16 KB store of transposed tile at tile-slot (R=bj, C=bi)
    unsigned char* tbase = K8 + (size_t)((bj * (bj + 1)) / 2 + bi) * 16384;
    #pragma unroll
    for (int it = 0; it < 2; ++it) {
        int c = it * 64 + (t >> 3);          // local row in stored tile, 0..127
        int dq = (t & 7) * 4;
        int g2 = ((c & 15) << 1) | ((c >> 3) & 1);
        uint4 wv;
        wv.x = sh.Tl[c * 32 + ((dq + 0) ^ g2)];
        wv.y = sh.Tl[c * 32 + ((dq + 1) ^ g2)];
        wv.z = sh.Tl[c * 32 + ((dq + 2) ^ g2)];
        wv.w = sh.Tl[c * 32 + ((dq + 3) ^ g2)];
        *(uint4*)(tbase + c * 128 + dq * 4) = wv;
    }
}

// One Sinkhorn pass, 1088 half-row work blocks, XCD-affine (R18 sink_map).
// Block (R,s,h): reads half-tiles (rows [h*64,h*64+64)) of tiles (R, 4s..4s+3) —
// each an 8 KB contiguous stream, L2-resident per XCD across passes.
__global__ __launch_bounds__(256, 4) void sink_pass_kernel(const unsigned char* __restrict__ K8,
                                                           const float* __restrict__ yprev,
                                                           float* __restrict__ ycur,
                                                           float* __restrict__ ynext,
                                                           const unsigned int* __restrict__ minslot) {
    __shared__ float xsc[512];
    __shared__ float xsr[64];
    __shared__ float rdp[64 * 33];
    __shared__ float csum[4 * 512];
    const int t = threadIdx.x;
    const int id = blockIdx.x;
    if (id < 32) ynext[id * 256 + t] = 0.0f;

    int R, s, h;
    sink_map(id, R, s, h);
    const int q0 = s * 4;
    const int rbase = R * 128 + h * 64;
    if (t < 64) xsr[t] = 1.0f / yprev[rbase + t];
    xsc[t]       = 1.0f / yprev[q0 * 128 + t];
    xsc[t + 256] = 1.0f / yprev[q0 * 128 + 256 + t];

    const int w = t >> 6, lane = t & 63, half = lane >> 5, d = lane & 31;
    const int ct = d >> 3;              // column tile within the 4-span
    const int C = q0 + ct;
    const bool tvalid = (C <= R);
    const bool cvalid = (C < R);

    // tile-major: tile (R,C) at (R(R+1)/2 + C)*16384, row-major 128B rows
    uint4 kreg[8];
    const unsigned char* base = K8 + (size_t)((R * (R + 1)) / 2 + C) * 16384
                                   + (h * 64 + (w << 4) + half) * 128 + (d & 7) * 16;
    if (tvalid) {
        #pragma unroll
        for (int i2 = 0; i2 < 8; ++i2)
            kreg[i2] = *(const uint4*)(base + (i2 << 1) * 128);
    } else {
        #pragma unroll
        for (int i2 = 0; i2 < 8; ++i2) kreg[i2] = (uint4){0u, 0u, 0u, 0u};
    }
    __syncthreads();

    float xr[16];
    #pragma unroll
    for (int u = 0; u < 4; ++u)
        *(float4*)&xr[u * 4] = *(const float4*)&xsc[d * 16 + u * 4];
    float ca[16];
    #pragma unroll
    for (int e = 0; e < 16; ++e) ca[e] = 0.0f;

    #pragma unroll
    for (int i2 = 0; i2 < 8; ++i2) {
        int row = (w << 4) + (i2 << 1) + half;
        float f[16];
        fp8x4_to_f32(kreg[i2].x, f + 0);  fp8x4_to_f32(kreg[i2].y, f + 4);
        fp8x4_to_f32(kreg[i2].z, f + 8);  fp8x4_to_f32(kreg[i2].w, f + 12);
        float rd = 0.0f;
        #pragma unroll
        for (int e = 0; e < 16; ++e) rd += f[e] * xr[e];
        if (cvalid) {
            float xv = xsr[row];
            #pragma unroll
            for (int e = 0; e < 16; ++e) ca[e] += f[e] * xv;
        }
        rdp[row * 33 + d] = rd;
    }
    #pragma unroll
    for (int e = 0; e < 16; ++e) ca[e] += __shfl_xor(ca[e], 32);
    if (half == 0) {
        #pragma unroll
        for (int u = 0; u < 4; ++u) {
            float4 v; v.x = ca[u*4]; v.y = ca[u*4+1]; v.z = ca[u*4+2]; v.w = ca[u*4+3];
            *(float4*)&csum[w * 512 + d * 16 + u * 4] = v;
        }
    }
    __syncthreads();
    if (t < 64) {
        float sum = 0.0f;
        #pragma unroll
        for (int k = 0; k < 32; ++k) sum += rdp[t * 33 + k];
        if (s == (R >> 2))
            sum += __expf(10.0f * fkey_inv(*minslot)) * xsr[t];
        atomicAdd(&ycur[rbase + t], sum);
    }
    #pragma unroll
    for (int u = 0; u < 2; ++u) {
        int cc = t + u * 256;
        int Cc = q0 + (cc >> 7);
        if (Cc < R)
            atomicAdd(&ycur[q0 * 128 + cc],
                      csum[cc] + csum[512 + cc] + csum[1024 + cc] + csum[1536 + cc]);
    }
}

// Final loss: pair term already in lossacc; add sum_i (10 - log y11[i] - log y10[i]).
__global__ __launch_bounds__(256) void loss_kernel(const float* __restrict__ y11,
                                                   const float* __restrict__ y10,
                                                   float* __restrict__ lossacc,
                                                   unsigned int* __restrict__ cnt,
                                                   float* __restrict__ out) {
    __shared__ float wpart[4];
    const int t = threadIdx.x;
    int i = blockIdx.x * 256 + t;
    float val = 10.0f - __logf(y11[i]) - __logf(y10[i]);
    #pragma unroll
    for (int off = 32; off; off >>= 1) val += __shfl_xor(val, off);
    if ((t & 63) == 0) wpart[t >> 6] = val;
    __syncthreads();
    if (t == 0) {
        atomicAdd(lossacc, wpart[0] + wpart[1] + wpart[2] + wpart[3]);
        __threadfence();
        unsigned int done = atomicAdd(cnt, 1u);
        if (done == gridDim.x - 1) {
            __threadfence();
            out[0] = -(*(volatile float*)lossacc) / (float)S_DIM;
        }
    }
}

extern "C" void kernel_launch(void* const* d_in, const int* in_sizes, int n_in,
                              void* d_out, int out_size, void* d_ws, size_t ws_size,
                              hipStream_t stream) {
    const float* z = (const float*)d_in[0];
    float* out = (float*)d_out;
    char* ws = (char*)d_ws;

    unsigned int* znb  = (unsigned int*)ws;                       // 2 MB bf16 fragment-major
    float* y0          = (float*)(ws + (2 << 20));                // 32 KB y buffers x3
    float* y1          = (float*)(ws + (2 << 20) + 65536);
    float* y2          = (float*)(ws + (2 << 20) + 131072);
    unsigned int* mins = (unsigned int*)(ws + (2 << 20) + 196608);
    float* lossacc     = (float*)(ws + (2 << 20) + 196608 + 64);
    unsigned int* cnt  = (unsigned int*)(ws + (2 << 20) + 196608 + 128);
    unsigned char* K8  = (unsigned char*)(ws + (8 << 20));        // 34 MB fp8 K' tile-major

    float* ybuf[3] = {y0, y1, y2};

    normalize_kernel<<<S_DIM / 4, 256, 0, stream>>>(z, znb, y0, y1, mins, lossacc, cnt);
    gemm_exp_mfma<<<NTRI, 512, 0, stream>>>((const short*)znb, K8, mins, lossacc);

    // pass p: x = 1/ybuf[(p-1)%3]; accumulate ybuf[p%3]; zero ybuf[(p+1)%3]
    for (int p = 1; p <= 11; ++p)
        sink_pass_kernel<<<NWORK2, 256, 0, stream>>>(K8, ybuf[(p - 1) % 3], ybuf[p % 3],
                                                     ybuf[(p + 1) % 3], mins);

    // y10 = ybuf[10%3]=y1, y11 = ybuf[11%3]=y2
    loss_kernel<<<S_DIM / 256, 256, 0, stream>>>(y2, y1, lossacc, cnt, out);
}